// Round 5
// baseline (1255.952 us; speedup 1.0000x reference)
//
#include <hip/hip_runtime.h>
#include <math.h>

#define BB 32
#define LL 40
#define DD 128
#define NSB 64                         // 2 seq * 32 batch
#define NU  (NSB * LL)                 // 2560
#define PLANE (DD * DD)                // 16384
#define NROW0 63                       // lev0 rows (no h-recurrence)
#define NPX0 (NROW0 * DD)              // 8064
#define H1SLAB ((size_t)NSB * PLANE)   // u16 per h1 t-slab
#define H2SLAB ((size_t)NSB * NPX0)    // u16 per h2 t-slab (rows 0..62 only)
#define GSLAB  ((size_t)NSB * NPX0)    // u16 per gate t-slab

typedef unsigned short u16;
typedef unsigned int u32;

__device__ __forceinline__ u16 f2bf(float f) {
    union { float f; unsigned u; } v; v.f = f;
    unsigned u = v.u;
    u += 0x7fff + ((u >> 16) & 1);     // RNE
    return (u16)(u >> 16);
}
__device__ __forceinline__ float bf2f(u16 b) {
    union { unsigned u; float f; } v; v.u = ((unsigned)b) << 16;
    return v.f;
}
__device__ __forceinline__ float sigm(float x)  { return 1.f / (1.f + __expf(-x)); }
// tanh(x) = 2*sigmoid(2x)-1 ; safe at extremes
__device__ __forceinline__ float tanhs(float x) { return 2.f / (1.f + __expf(-2.f * x)) - 1.f; }

// ---------------- prep: xe rows + inverse squared norms ----------------
__global__ void prep_kernel(const int* __restrict__ q, const int* __restrict__ a,
                            const float* __restrict__ embed,
                            float* __restrict__ xe_all, float* __restrict__ inv_all) {
    int u = blockIdx.x * 4 + (threadIdx.x >> 6);
    int lane = threadIdx.x & 63;
    if (u >= NU) return;
    int sb = u / LL, t = u % LL;
    int s = sb >> 5, b = sb & 31;
    const int* idx = s ? a : q;
    int e = idx[b * LL + t];
    const float* row = embed + (size_t)e * DD;
    float v0 = row[lane], v1 = row[lane + 64];
    xe_all[(size_t)u * DD + lane] = v0;
    xe_all[(size_t)u * DD + lane + 64] = v1;
    float d = v0 * v0 + v1 * v1;
    #pragma unroll
    for (int o = 32; o; o >>= 1) d += __shfl_down(d, o);
    if (lane == 0) inv_all[u] = 1.f / (d + 1e-4f);
}

// ---------------- layer1 lev0 gates: t-parallel, separable density conv ----------------
// grid (LL, NSB), block 1024. Writes fg, ig*cs, og as bf16.
__global__ __launch_bounds__(1024)
void l1_gates_kernel(const float* __restrict__ xe_all, const float* __restrict__ inv_all,
                     const float* __restrict__ conv_w, const float* __restrict__ conv_b,
                     u16* __restrict__ gfg, u16* __restrict__ gic, u16* __restrict__ gog) {
    const int t = blockIdx.x, sb = blockIdx.y;
    const int u = sb * LL + t;
    const int tid = threadIdx.x;
    __shared__ float xe_s[DD + 2];     // data at [c+1], pads 0
    __shared__ float U[NROW0][12];
    __shared__ float wls[48], bls[4];
    if (tid < 48) wls[tid] = conv_w[tid];
    if (tid < 4)  bls[tid] = conv_b[tid];
    if (tid < DD) xe_s[tid + 1] = xe_all[(size_t)u * DD + tid];
    if (tid == DD) { xe_s[0] = 0.f; xe_s[DD + 1] = 0.f; }
    __syncthreads();
    // U[i][g*3+kw] = sum_kh w[g][kh][kw] * xe[2i-1+kh]
    for (int e = tid; e < NROW0 * 12; e += 1024) {
        int i = e / 12, k = e - i * 12;
        int g = k / 3, kw = k - g * 3;
        int base = 2 * i - 1;
        float s = 0.f;
        #pragma unroll
        for (int kh = 0; kh < 4; ++kh) {
            int r = base + kh;
            float v = (r >= 0 && r < DD) ? xe_s[r + 1] : 0.f;
            s += wls[g * 12 + kh * 3 + kw] * v;
        }
        U[i][k] = s;
    }
    __syncthreads();
    const float invv = inv_all[u];
    const size_t gb = (size_t)t * GSLAB + (size_t)sb * NPX0;
    u16* pf = gfg + gb; u16* pi = gic + gb; u16* po = gog + gb;
    for (int px = tid; px < NPX0; px += 1024) {
        int i = px >> 7, c = px & 127;
        float xl = xe_s[c], xm = xe_s[c + 1], xr = xe_s[c + 2];
        float a0 = bls[0] + invv * (U[i][0] * xl + U[i][1]  * xm + U[i][2]  * xr);
        float a1 = bls[1] + invv * (U[i][3] * xl + U[i][4]  * xm + U[i][5]  * xr);
        float a2 = bls[2] + invv * (U[i][6] * xl + U[i][7]  * xm + U[i][8]  * xr);
        float a3 = bls[3] + invv * (U[i][9] * xl + U[i][10] * xm + U[i][11] * xr);
        pf[px] = f2bf(sigm(a0));
        pi[px] = f2bf(sigm(a1) * tanhs(a3));
        po[px] = f2bf(sigm(a2));
    }
}

// ---------------- layer2 lev0 gates: t-parallel, direct 4x3 conv from h1[t] ----------------
// grid (LL, NSB), block 1024 = 128 cols x 8 row-groups (8 consecutive rows each).
__global__ __launch_bounds__(1024)
void l2_gates_kernel(const u16* __restrict__ h1,
                     const float* __restrict__ conv_w, const float* __restrict__ conv_b,
                     u16* __restrict__ gfg, u16* __restrict__ gic, u16* __restrict__ gog) {
    const int t = blockIdx.x, sb = blockIdx.y;
    const int tx = threadIdx.x & 127, ty = threadIdx.x >> 7;
    const int tid = threadIdx.x;
    __shared__ u16 win[128][132];      // win[w+1][c+2]; row 0 (w=-1) zero; col pads [1],[130] zero
    __shared__ float wls[48], bls[4];
    if (tid < 48) wls[tid] = conv_w[48 + tid];
    if (tid < 4)  bls[tid] = conv_b[4 + tid];
    if (tid < 132) win[0][tid] = 0;
    else if (tid < 259) win[tid - 131][1] = 0;
    else if (tid < 386) win[tid - 258][130] = 0;
    const u32* src = (const u32*)(h1 + (size_t)(t + 1) * H1SLAB + (size_t)sb * PLANE);
    for (int e = tid; e < 127 * 64; e += 1024) {
        int r = e >> 6, cp = e & 63;
        *(u32*)&win[r + 1][2 * cp + 2] = src[r * 64 + cp];
    }
    __syncthreads();
    const size_t gb = (size_t)t * GSLAB + (size_t)sb * NPX0;
    u16* pf = gfg + gb; u16* pi = gic + gb; u16* po = gog + gb;
    #pragma unroll
    for (int k = 0; k < 8; ++k) {
        if (k == 7 && ty == 7) break;              // i=63 invalid
        const int i = 8 * ty + k;
        float a0 = bls[0], a1 = bls[1], a2 = bls[2], a3 = bls[3];
        #pragma unroll
        for (int kh = 0; kh < 4; ++kh) {
            #pragma unroll
            for (int kw = 0; kw < 3; ++kw) {
                float v = bf2f(win[16 * ty + 2 * k + kh][tx + 1 + kw]);
                a0 += v * wls[kh * 3 + kw];
                a1 += v * wls[12 + kh * 3 + kw];
                a2 += v * wls[24 + kh * 3 + kw];
                a3 += v * wls[36 + kh * 3 + kw];
            }
        }
        const int px = i * DD + tx;
        pf[px] = f2bf(sigm(a0));
        pi[px] = f2bf(sigm(a1) * tanhs(a3));
        po[px] = f2bf(sigm(a2));
    }
}

// ---------------- scan: pointwise c-recurrence over t for lev0 rows ----------------
__global__ __launch_bounds__(256)
void scan_kernel(const u16* __restrict__ gfg, const u16* __restrict__ gic,
                 const u16* __restrict__ gog,
                 u16* __restrict__ hdst, long hslab, long hsbstride,
                 float* __restrict__ pool) {
    const int id = blockIdx.x * 256 + threadIdx.x;
    const int sb = id / NPX0;
    const int px = id - sb * NPX0;
    const size_t g = (size_t)sb * NPX0 + px;
    const u16* pf = gfg + g;
    const u16* pi = gic + g;
    const u16* po = gog + g;
    u16* ph = hdst + (size_t)hslab + (size_t)sb * hsbstride + px;   // slab 1 (t=0)
    float c = 0.f, pr = -1e30f;
    for (int t = 0; t < LL; ++t) {
        float fg = bf2f(*pf), ic = bf2f(*pi), og = bf2f(*po);
        c = fg * c + ic;
        float h = og * tanhs(c);
        *ph = f2bf(h);
        pr = fmaxf(pr, h);
        pf += GSLAB; pi += GSLAB; po += GSLAB; ph += hslab;
    }
    if (pool) pool[(size_t)sb * PLANE + px] = pr;
}

// ---------------- upper rows 63..127: one block per sb, LDS-resident state ----------------
// block 1024 = 128 cols x 8 ty; thread owns rows 63+8ty..70+8ty (ty==7 also row 127).
__global__ __launch_bounds__(1024)
void upper_kernel(const float* __restrict__ xe_all, const float* __restrict__ inv_all,
                  const u16* __restrict__ xt_src,   // layer2: h1 base; layer1: null (density)
                  const u16* __restrict__ low_src,  // own lower rows (slab layout base)
                  long low_slab, long low_sbstride,
                  u16* __restrict__ h_out,          // layer1: h1 base; layer2: null
                  const float* __restrict__ conv_w, const float* __restrict__ conv_b,
                  float* __restrict__ pool, int layer) {
    const int sb = blockIdx.x;
    const int tx = threadIdx.x & 127, ty = threadIdx.x >> 7;
    const int tid = threadIdx.x;
    __shared__ u16 oh[129][132];       // own h rows 0..127 (t-1), data [c+2]; row 128 + pads = 0
    __shared__ float xt_s[3][132];     // concat rows 125..127 at t, data [c+2]
    __shared__ float wls[48], bls[4];
    if (tid < 48) wls[tid] = conv_w[layer * 48 + tid];
    if (tid < 4)  bls[tid] = conv_b[layer * 4 + tid];
    for (int e = tid; e < 129 * 66; e += 1024) ((u32*)oh)[e] = 0;
    if (tid < 6) xt_s[tid >> 1][(tid & 1) ? 130 : 1] = 0.f;

    const u32* lsrc = (const u32*)(low_src + (size_t)sb * low_sbstride);
    const u16* xsrc = xt_src ? xt_src + H1SLAB + (size_t)sb * PLANE + (size_t)125 * DD : nullptr;
    u16* hout = h_out ? h_out + H1SLAB + (size_t)sb * PLANE : nullptr;
    const float* xe_u = xe_all + (size_t)(sb * LL) * DD;
    const float* inv_u = inv_all + sb * LL;

    float cst[9], prm[9];
    #pragma unroll
    for (int k = 0; k < 9; ++k) { cst[k] = 0.f; prm[k] = -1e30f; }

    for (int t = 0; t < LL; ++t) {
        // stage own lower rows 0..62 (t-1 values); disjoint from prev writeback (rows 63..127)
        for (int e = tid; e < NROW0 * 64; e += 1024) {
            int r = e >> 6, cp = e & 63;
            *(u32*)&oh[r][2 * cp + 2] = lsrc[r * 64 + cp];
        }
        if (xsrc) {
            if (tid < 384) {
                int r = tid >> 7, c = tid & 127;
                xt_s[r][c + 2] = bf2f(xsrc[r * DD + c]);
            }
        } else {
            if (tid < 384) {
                int r = tid >> 7, c = tid & 127;
                xt_s[r][c + 2] = xe_u[125 + r] * xe_u[c] * inv_u[0];
            }
        }
        __syncthreads();

        float hnew[9];
        #pragma unroll
        for (int k = 0; k < 9; ++k) {
            if (k == 8 && ty != 7) break;          // only ty==7 owns row 127
            float a0 = bls[0], a1 = bls[1], a2 = bls[2], a3 = bls[3];
            if (ty == 0 && k < 2) {
                // i = 63+k : window rows 125+2k .. 128+2k mix xt rows and own rows
                #pragma unroll
                for (int kh = 0; kh < 4; ++kh) {
                    int w = 125 + 2 * k + kh;
                    #pragma unroll
                    for (int kw = 0; kw < 3; ++kw) {
                        float v = (w < 128) ? xt_s[w - 125][tx + 1 + kw]
                                            : bf2f(oh[w - 128][tx + 1 + kw]);
                        a0 += v * wls[kh * 3 + kw];
                        a1 += v * wls[12 + kh * 3 + kw];
                        a2 += v * wls[24 + kh * 3 + kw];
                        a3 += v * wls[36 + kh * 3 + kw];
                    }
                }
            } else {
                const int rb = 16 * ty + 2 * k - 3;    // own row for kh=0 (>=1 here)
                #pragma unroll
                for (int kh = 0; kh < 4; ++kh) {
                    #pragma unroll
                    for (int kw = 0; kw < 3; ++kw) {
                        float v = bf2f(oh[rb + kh][tx + 1 + kw]);
                        a0 += v * wls[kh * 3 + kw];
                        a1 += v * wls[12 + kh * 3 + kw];
                        a2 += v * wls[24 + kh * 3 + kw];
                        a3 += v * wls[36 + kh * 3 + kw];
                    }
                }
            }
            float fg = sigm(a0), ig = sigm(a1), og = sigm(a2), cs = tanhs(a3);
            cst[k] = fg * cst[k] + ig * cs;
            float hn = og * tanhs(cst[k]);
            hnew[k] = hn;
            prm[k] = fmaxf(prm[k], hn);
        }
        __syncthreads();                            // all reads of oh (t-1) done
        #pragma unroll
        for (int k = 0; k < 9; ++k) {
            if (k == 8 && ty != 7) break;
            const int myr = 63 + 8 * ty + k;
            u16 hb = f2bf(hnew[k]);
            oh[myr][tx + 2] = hb;
            if (hout) hout[(size_t)myr * DD + tx] = hb;
        }
        lsrc += low_slab / 2;
        if (xsrc) xsrc += H1SLAB;
        if (hout) hout += H1SLAB;
        xe_u += DD; inv_u += 1;
    }
    if (pool) {
        #pragma unroll
        for (int k = 0; k < 9; ++k) {
            if (k == 8 && ty != 7) break;
            const int myr = 63 + 8 * ty + k;
            pool[(size_t)sb * PLANE + (size_t)myr * DD + tx] = prm[k];
        }
    }
}

// ---------------- final: linear + log_softmax ----------------
__global__ void final_kernel(const float* __restrict__ pool,
                             const float* __restrict__ lin_w,
                             const float* __restrict__ lin_b,
                             float* __restrict__ out) {
    const int b = blockIdx.x;
    const int tid = threadIdx.x;  // 256
    const int DD2 = DD * DD;
    const float* pq = pool + (size_t)b * DD2;
    const float* pa = pool + (size_t)(BB + b) * DD2;
    float s0 = 0.f, s1 = 0.f;
    for (int j = tid; j < DD2; j += 256) {
        float vq = pq[j], va = pa[j];
        s0 += vq * lin_w[j]           + va * lin_w[DD2 + j];
        s1 += vq * lin_w[2 * DD2 + j] + va * lin_w[3 * DD2 + j];
    }
    #pragma unroll
    for (int o = 32; o; o >>= 1) {
        s0 += __shfl_down(s0, o);
        s1 += __shfl_down(s1, o);
    }
    __shared__ float sh0[4], sh1[4];
    int wid = tid >> 6, lane = tid & 63;
    if (lane == 0) { sh0[wid] = s0; sh1[wid] = s1; }
    __syncthreads();
    if (tid == 0) {
        float a0 = sh0[0] + sh0[1] + sh0[2] + sh0[3] + lin_b[0];
        float a1 = sh1[0] + sh1[1] + sh1[2] + sh1[3] + lin_b[1];
        float m = fmaxf(a0, a1);
        float lse = m + logf(expf(a0 - m) + expf(a1 - m));
        out[b * 2 + 0] = a0 - lse;
        out[b * 2 + 1] = a1 - lse;
    }
}

extern "C" void kernel_launch(void* const* d_in, const int* in_sizes, int n_in,
                              void* d_out, int out_size, void* d_ws, size_t ws_size,
                              hipStream_t stream) {
    const int*   q      = (const int*)d_in[0];
    const int*   a      = (const int*)d_in[1];
    const float* embed  = (const float*)d_in[2];
    const float* conv_w = (const float*)d_in[3];
    const float* conv_b = (const float*)d_in[4];
    const float* lin_w  = (const float*)d_in[5];
    const float* lin_b  = (const float*)d_in[6];
    float* out = (float*)d_out;

    // ws layout: xe 1.3MB | inv | pool 4.2MB | h1 86MB (41 slabs, 128 rows)
    //            | h2 42.3MB (41 slabs, 63 rows) | gates 3x41.3MB  => ~258MB
    float* ws      = (float*)d_ws;
    float* xe_all  = ws;
    float* inv_all = xe_all + (size_t)NU * DD;
    float* pool    = inv_all + NU;
    u16*   h1      = (u16*)(pool + (size_t)NSB * PLANE);
    u16*   h2      = h1 + (size_t)(LL + 1) * H1SLAB;
    u16*   gfg     = h2 + (size_t)(LL + 1) * H2SLAB;
    u16*   gic     = gfg + (size_t)LL * GSLAB;
    u16*   gog     = gic + (size_t)LL * GSLAB;

    // zero the t = -1 slabs
    hipMemsetAsync(h1, 0, H1SLAB * sizeof(u16), stream);
    hipMemsetAsync(h2, 0, H2SLAB * sizeof(u16), stream);

    prep_kernel<<<(NU + 3) / 4, 256, 0, stream>>>(q, a, embed, xe_all, inv_all);

    // ---- layer 1 ----
    l1_gates_kernel<<<dim3(LL, NSB), 1024, 0, stream>>>(xe_all, inv_all, conv_w, conv_b,
                                                        gfg, gic, gog);
    scan_kernel<<<NSB * NPX0 / 256, 256, 0, stream>>>(gfg, gic, gog,
                                                      h1, (long)H1SLAB, (long)PLANE, nullptr);
    upper_kernel<<<NSB, 1024, 0, stream>>>(xe_all, inv_all, nullptr,
                                           h1, (long)H1SLAB, (long)PLANE,
                                           h1, conv_w, conv_b, nullptr, 0);
    // ---- layer 2 ----
    l2_gates_kernel<<<dim3(LL, NSB), 1024, 0, stream>>>(h1, conv_w, conv_b, gfg, gic, gog);
    scan_kernel<<<NSB * NPX0 / 256, 256, 0, stream>>>(gfg, gic, gog,
                                                      h2, (long)H2SLAB, (long)NPX0, pool);
    upper_kernel<<<NSB, 1024, 0, stream>>>(xe_all, inv_all, h1,
                                           h2, (long)H2SLAB, (long)NPX0,
                                           nullptr, conv_w, conv_b, pool, 1);

    final_kernel<<<BB, 256, 0, stream>>>(pool, lin_w, lin_b, out);
}